// Round 3
// baseline (448.508 us; speedup 1.0000x reference)
//
#include <hip/hip_runtime.h>
#include <hip/hip_bf16.h>
#include <stdint.h>

#define D_DIM 1024
#define NH 16
#define DHD 64
#define SEQ 64
#define NBATCH 256
#define M_TOT 16384            // NBATCH*SEQ
#define ATT_SCALE 0.125f       // 64^-0.5
#define LN_EPS 1e-5f

typedef __attribute__((ext_vector_type(8))) short bf16x8;
typedef __attribute__((ext_vector_type(4))) float f32x4;

__device__ __forceinline__ float bf2f(short s) {
  union { uint32_t u; float f; } c;
  c.u = ((uint32_t)(uint16_t)s) << 16;
  return c.f;
}

__device__ __forceinline__ short f2bf(float f) {
  __hip_bfloat16 h = __float2bfloat16(f);
  union { __hip_bfloat16 h; short s; } c; c.h = h;
  return c.s;
}

// convert 8 fp32 (two float4) -> bf16x8
__device__ __forceinline__ bf16x8 cvt8(float4 a, float4 b) {
  bf16x8 r;
  r[0] = f2bf(a.x); r[1] = f2bf(a.y); r[2] = f2bf(a.z); r[3] = f2bf(a.w);
  r[4] = f2bf(b.x); r[5] = f2bf(b.y); r[6] = f2bf(b.z); r[7] = f2bf(b.w);
  return r;
}

// ---------------------------------------------------------------------------
// Kernel 1: QKV projection. Inputs fp32; convert to bf16 while staging to LDS.
// C[m,n] = sum_k A[m,k] * W[n,k]  (x @ W^T). 128x128 tile, BK=32, 4 waves.
// z<2 -> out [B,H,seq,dh]; z==2 -> out [B,H,dh,seq] (V transposed).
// ---------------------------------------------------------------------------
__global__ void gemm_qkv(const float* __restrict__ A,
                         const float* __restrict__ Wq,
                         const float* __restrict__ Wk,
                         const float* __restrict__ Wv,
                         __hip_bfloat16* __restrict__ Qw,
                         __hip_bfloat16* __restrict__ Kw,
                         __hip_bfloat16* __restrict__ Vtw) {
  __shared__ __align__(16) __hip_bfloat16 As[128 * 32];
  __shared__ __align__(16) __hip_bfloat16 Bs[128 * 32];
  const int tid = threadIdx.x;
  const int lane = tid & 63;
  const int wave = tid >> 6;
  const int l16 = lane & 15, kq = lane >> 4;       // kq in 0..3
  const int m0 = blockIdx.x * 128, n0 = blockIdx.y * 128;
  const int z = blockIdx.z;
  const float* Bm = (z == 0) ? Wq : (z == 1) ? Wk : Wv;
  const int wr = (wave >> 1) * 64, wc = (wave & 1) * 64;

  f32x4 acc[4][4] = {};

  for (int kk = 0; kk < D_DIM; kk += 32) {
#pragma unroll
    for (int i = 0; i < 2; ++i) {
      int chunk = i * 256 + tid;                   // 0..511, 8-elt chunk id
      int r = chunk >> 2, c = (chunk & 3) << 3;    // tile row / col
      const float* pa = A + (size_t)(m0 + r) * D_DIM + kk + c;
      const float* pb = Bm + (size_t)(n0 + r) * D_DIM + kk + c;
      float4 a0 = ((const float4*)pa)[0], a1 = ((const float4*)pa)[1];
      float4 b0 = ((const float4*)pb)[0], b1 = ((const float4*)pb)[1];
      *(bf16x8*)((short*)As + chunk * 8) = cvt8(a0, a1);
      *(bf16x8*)((short*)Bs + chunk * 8) = cvt8(b0, b1);
    }
    __syncthreads();
    bf16x8 af[4], bfr[4];
#pragma unroll
    for (int i = 0; i < 4; ++i)
      af[i] = *(const bf16x8*)((const short*)As + (wr + i * 16 + l16) * 32 + kq * 8);
#pragma unroll
    for (int j = 0; j < 4; ++j)
      bfr[j] = *(const bf16x8*)((const short*)Bs + (wc + j * 16 + l16) * 32 + kq * 8);
#pragma unroll
    for (int i = 0; i < 4; ++i)
#pragma unroll
      for (int j = 0; j < 4; ++j)
        acc[i][j] = __builtin_amdgcn_mfma_f32_16x16x32_bf16(af[i], bfr[j], acc[i][j], 0, 0, 0);
    __syncthreads();
  }

  __hip_bfloat16* outp = (z == 0) ? Qw : (z == 1) ? Kw : Vtw;
#pragma unroll
  for (int i = 0; i < 4; ++i) {
#pragma unroll
    for (int r = 0; r < 4; ++r) {
      int gm = m0 + wr + i * 16 + kq * 4 + r;      // token index
      int b = gm >> 6, ks = gm & 63;
#pragma unroll
      for (int j = 0; j < 4; ++j) {
        int gn = n0 + wc + j * 16 + l16;           // feature index
        int h = gn >> 6, dh = gn & 63;
        size_t idx = (z < 2)
            ? ((size_t)(b * NH + h) * SEQ + ks) * DHD + dh
            : ((size_t)(b * NH + h) * DHD + dh) * SEQ + ks;
        outp[idx] = __float2bfloat16(acc[i][j][r]);
      }
    }
  }
}

// ---------------------------------------------------------------------------
// Kernel 2: attention, one block per (b,h). All-bf16 workspace I/O.
// Q,K: [64 seq][64 dh]; Vt: [64 dh][64 seq]. O written in-place into Q slice.
// ---------------------------------------------------------------------------
__global__ void attn_k(__hip_bfloat16* Qw,                 // in: Q, out: O (aliased)
                       const __hip_bfloat16* __restrict__ Kw,
                       const __hip_bfloat16* __restrict__ Vtw,
                       const int* __restrict__ mask) {
  __shared__ __align__(16) __hip_bfloat16 Qs[4096];
  __shared__ __align__(16) __hip_bfloat16 Ks[4096];
  __shared__ __align__(16) __hip_bfloat16 Vs[4096];
  __shared__ __align__(16) __hip_bfloat16 Ps[4096];
  const int tid = threadIdx.x;
  const int lane = tid & 63;
  const int wave = tid >> 6;
  const int l16 = lane & 15, kq = lane >> 4;
  const int w16 = wave * 16;
  const size_t base = (size_t)blockIdx.x * 4096;

#pragma unroll
  for (int i = 0; i < 2; ++i) {
    int chunk = i * 256 + tid;
    bf16x8 vq = *(const bf16x8*)(Qw + base + chunk * 8);
    bf16x8 vk = *(const bf16x8*)(Kw + base + chunk * 8);
    bf16x8 vv = *(const bf16x8*)(Vtw + base + chunk * 8);
    *(bf16x8*)((short*)Qs + chunk * 8) = vq;
    *(bf16x8*)((short*)Ks + chunk * 8) = vk;
    *(bf16x8*)((short*)Vs + chunk * 8) = vv;
  }
  __syncthreads();

  // S = Q @ K^T  (wave handles 16 query rows x 64 key cols)
  f32x4 accS[4] = {};
#pragma unroll
  for (int kk = 0; kk < 64; kk += 32) {
    bf16x8 a = *(const bf16x8*)((const short*)Qs + (w16 + l16) * 64 + kk + kq * 8);
#pragma unroll
    for (int j = 0; j < 4; ++j) {
      bf16x8 b = *(const bf16x8*)((const short*)Ks + (j * 16 + l16) * 64 + kk + kq * 8);
      accS[j] = __builtin_amdgcn_mfma_f32_16x16x32_bf16(a, b, accS[j], 0, 0, 0);
    }
  }

  // row softmax: row q = w16 + kq*4 + r, col s = j*16 + l16
#pragma unroll
  for (int r = 0; r < 4; ++r) {
    float sv[4];
    float m = -1e30f;
#pragma unroll
    for (int j = 0; j < 4; ++j) { sv[j] = accS[j][r] * ATT_SCALE; m = fmaxf(m, sv[j]); }
#pragma unroll
    for (int off = 1; off < 16; off <<= 1) m = fmaxf(m, __shfl_xor(m, off, 64));
    float s = 0.f;
#pragma unroll
    for (int j = 0; j < 4; ++j) { sv[j] = __expf(sv[j] - m); s += sv[j]; }
#pragma unroll
    for (int off = 1; off < 16; off <<= 1) s += __shfl_xor(s, off, 64);
    float inv = 1.0f / s;
    int row = w16 + kq * 4 + r;
#pragma unroll
    for (int j = 0; j < 4; ++j)
      Ps[row * 64 + j * 16 + l16] = __float2bfloat16(sv[j] * inv);
  }
  __syncthreads();

  // O = P @ V   (Vs holds V^T: row d, col s)
  f32x4 accO[4] = {};
#pragma unroll
  for (int kk = 0; kk < 64; kk += 32) {
    bf16x8 a = *(const bf16x8*)((const short*)Ps + (w16 + l16) * 64 + kk + kq * 8);
#pragma unroll
    for (int j = 0; j < 4; ++j) {
      bf16x8 b = *(const bf16x8*)((const short*)Vs + (j * 16 + l16) * 64 + kk + kq * 8);
      accO[j] = __builtin_amdgcn_mfma_f32_16x16x32_bf16(a, b, accO[j], 0, 0, 0);
    }
  }

  // write O into the (b,h) slice of Qw: layout [b][h][seq][dh]
  const int b = blockIdx.x >> 4;
#pragma unroll
  for (int r = 0; r < 4; ++r) {
    int q = w16 + kq * 4 + r;
    float mk = mask[b * SEQ + q] ? 1.0f : 0.0f;   // post-softmax query-row mask
#pragma unroll
    for (int j = 0; j < 4; ++j) {
      int d = j * 16 + l16;
      Qw[base + q * DHD + d] = __float2bfloat16(accO[j][r] * mk);
    }
  }
}

// ---------------------------------------------------------------------------
// Kernel 3: O projection + gated residual. Hf(fp32) = hidden + mask[m]*(O @ Wo^T)
// O input bf16 in [B,H,seq,dh]; Wo fp32 converted while staging.
// ---------------------------------------------------------------------------
__global__ void gemm_o(const __hip_bfloat16* __restrict__ Ow,   // [B,H,seq,dh]
                       const float* __restrict__ Wo,
                       const float* __restrict__ hidden,
                       const int* __restrict__ mask,
                       float* __restrict__ Hf) {
  __shared__ __align__(16) __hip_bfloat16 As[128 * 32];
  __shared__ __align__(16) __hip_bfloat16 Bs[128 * 32];
  const int tid = threadIdx.x;
  const int lane = tid & 63;
  const int wave = tid >> 6;
  const int l16 = lane & 15, kq = lane >> 4;
  const int m0 = blockIdx.x * 128, n0 = blockIdx.y * 128;
  const int wr = (wave >> 1) * 64, wc = (wave & 1) * 64;

  f32x4 acc[4][4] = {};

  for (int kk = 0; kk < D_DIM; kk += 32) {
#pragma unroll
    for (int i = 0; i < 2; ++i) {
      int chunk = i * 256 + tid;
      int r = chunk >> 2, c = (chunk & 3) << 3;
      // A element: token t = m0+r, feature f = kk+c (8 contiguous, same head)
      int t = m0 + r, f = kk + c;
      int b = t >> 6, s = t & 63, h = f >> 6, dh = f & 63;
      bf16x8 va = *(const bf16x8*)(Ow + ((size_t)((b << 4) + h) << 12) + (s << 6) + dh);
      const float* pb = Wo + (size_t)(n0 + r) * D_DIM + kk + c;
      float4 b0 = ((const float4*)pb)[0], b1 = ((const float4*)pb)[1];
      *(bf16x8*)((short*)As + chunk * 8) = va;
      *(bf16x8*)((short*)Bs + chunk * 8) = cvt8(b0, b1);
    }
    __syncthreads();
    bf16x8 af[4], bfr[4];
#pragma unroll
    for (int i = 0; i < 4; ++i)
      af[i] = *(const bf16x8*)((const short*)As + (wr + i * 16 + l16) * 32 + kq * 8);
#pragma unroll
    for (int j = 0; j < 4; ++j)
      bfr[j] = *(const bf16x8*)((const short*)Bs + (wc + j * 16 + l16) * 32 + kq * 8);
#pragma unroll
    for (int i = 0; i < 4; ++i)
#pragma unroll
      for (int j = 0; j < 4; ++j)
        acc[i][j] = __builtin_amdgcn_mfma_f32_16x16x32_bf16(af[i], bfr[j], acc[i][j], 0, 0, 0);
    __syncthreads();
  }

#pragma unroll
  for (int i = 0; i < 4; ++i) {
#pragma unroll
    for (int r = 0; r < 4; ++r) {
      int gm = m0 + wr + i * 16 + kq * 4 + r;
      float mk = mask[gm] ? 1.0f : 0.0f;
#pragma unroll
      for (int j = 0; j < 4; ++j) {
        int gn = n0 + wc + j * 16 + l16;
        size_t idx = (size_t)gm * D_DIM + gn;
        Hf[idx] = hidden[idx] + mk * acc[i][j][r];
      }
    }
  }
}

// ---------------------------------------------------------------------------
// Kernel 4: LayerNorm over D=1024, fp32 in/out. One row/block, 128 thr x 8.
// ---------------------------------------------------------------------------
__global__ void ln_k(const float* __restrict__ Hf,
                     const float* __restrict__ gamma,
                     const float* __restrict__ beta,
                     float* __restrict__ out) {
  __shared__ float red[4];
  const int row = blockIdx.x, tid = threadIdx.x;
  const int wave = tid >> 6, lane = tid & 63;
  const size_t boff = (size_t)row * D_DIM + tid * 8;

  float4 v0 = ((const float4*)(Hf + boff))[0];
  float4 v1 = ((const float4*)(Hf + boff))[1];
  float f[8] = {v0.x, v0.y, v0.z, v0.w, v1.x, v1.y, v1.z, v1.w};
  float s = 0.f, ss = 0.f;
#pragma unroll
  for (int k = 0; k < 8; ++k) { s += f[k]; ss += f[k] * f[k]; }
#pragma unroll
  for (int off = 1; off < 64; off <<= 1) {
    s += __shfl_xor(s, off, 64);
    ss += __shfl_xor(ss, off, 64);
  }
  if (lane == 0) { red[wave * 2] = s; red[wave * 2 + 1] = ss; }
  __syncthreads();
  s = red[0] + red[2];
  ss = red[1] + red[3];
  const float mu = s * (1.0f / D_DIM);
  const float var = ss * (1.0f / D_DIM) - mu * mu;
  const float rs = rsqrtf(var + LN_EPS);

  float4 g0 = ((const float4*)(gamma + tid * 8))[0];
  float4 g1 = ((const float4*)(gamma + tid * 8))[1];
  float4 b0 = ((const float4*)(beta + tid * 8))[0];
  float4 b1 = ((const float4*)(beta + tid * 8))[1];
  float g[8] = {g0.x, g0.y, g0.z, g0.w, g1.x, g1.y, g1.z, g1.w};
  float bb[8] = {b0.x, b0.y, b0.z, b0.w, b1.x, b1.y, b1.z, b1.w};
  float o[8];
#pragma unroll
  for (int k = 0; k < 8; ++k)
    o[k] = (f[k] - mu) * rs * g[k] + bb[k];
  ((float4*)(out + boff))[0] = make_float4(o[0], o[1], o[2], o[3]);
  ((float4*)(out + boff))[1] = make_float4(o[4], o[5], o[6], o[7]);
}

// ---------------------------------------------------------------------------
extern "C" void kernel_launch(void* const* d_in, const int* in_sizes, int n_in,
                              void* d_out, int out_size, void* d_ws, size_t ws_size,
                              hipStream_t stream) {
  const float* hidden = (const float*)d_in[0];
  const int* mask = (const int*)d_in[1];
  const float* Wq = (const float*)d_in[2];
  const float* Wk = (const float*)d_in[3];
  const float* Wv = (const float*)d_in[4];
  const float* Wo = (const float*)d_in[5];
  const float* gamma = (const float*)d_in[6];
  const float* beta = (const float*)d_in[7];
  float* out = (float*)d_out;

  const size_t SZ = (size_t)M_TOT * D_DIM;      // 16,777,216 elements
  __hip_bfloat16* Qw = (__hip_bfloat16*)d_ws;   // bf16 [B,H,seq,dh]; O in-place
  __hip_bfloat16* Kw = Qw + SZ;                 // bf16 [B,H,seq,dh]
  __hip_bfloat16* Vtw = Kw + SZ;                // bf16 [B,H,dh,seq]
  float* Hf = (float*)Kw;                       // fp32, reuses K+V region (67 MB)
                                                // total ws usage: 100.7 MB

  gemm_qkv<<<dim3(128, 8, 3), 256, 0, stream>>>(hidden, Wq, Wk, Wv, Qw, Kw, Vtw);
  attn_k<<<dim3(4096), 256, 0, stream>>>(Qw, Kw, Vtw, mask);
  gemm_o<<<dim3(128, 8), 256, 0, stream>>>(Qw, Wo, hidden, mask, Hf);
  ln_k<<<dim3(16384), 128, 0, stream>>>(Hf, gamma, beta, out);
}